// Round 6
// baseline (123.798 us; speedup 1.0000x reference)
//
#include <hip/hip_runtime.h>

// SSM DPLR kernel: K[h,l] = 2*Re(C_h . dA_h^l . dB_h), dA = diag(g) + q r^T.
// R5: same math as R4 (l = 64i+j, M = dA^64 divided-difference closed form,
// triangular-Toeplitz solves) but wave-internal broadcasts use v_readlane
// instead of uniform ds_read (~120cyc -> ~4cyc):
//  - wave0: sigma solve + X rebuild (sigma stays in registers)
//  - wave1: tau solve + Horner T(g),T'(g) (tau stays in registers)
//  - M build: g,q,g64 broadcasts via readlane from own lanes; only T(g) via LDS
//  - output: C rows via 4 vector LDS reads + readlane

#define LL 2048

struct C2 { float re, im; };

__device__ __forceinline__ C2 cmul(C2 a, C2 b){ return {a.re*b.re - a.im*b.im, a.re*b.im + a.im*b.re}; }
__device__ __forceinline__ C2 cadd(C2 a, C2 b){ return {a.re+b.re, a.im+b.im}; }
__device__ __forceinline__ C2 csub(C2 a, C2 b){ return {a.re-b.re, a.im-b.im}; }
__device__ __forceinline__ C2 cinv(C2 a){ float s=1.0f/(a.re*a.re+a.im*a.im); return {a.re*s, -a.im*s}; }
__device__ __forceinline__ C2 cscale(float s, C2 a){ return {s*a.re, s*a.im}; }
__device__ __forceinline__ C2 ld2(float2 v){ return {v.x, v.y}; }
__device__ __forceinline__ float2 st2(C2 v){ return make_float2(v.re, v.im); }

template<int CTRL>
__device__ __forceinline__ float dpp_add(float x){
  int t = __builtin_amdgcn_update_dpp(0, __float_as_int(x), CTRL, 0xF, 0xF, true);
  return x + __int_as_float(t);
}
__device__ __forceinline__ float wave_sum63(float x){
  x = dpp_add<0xB1>(x);   // quad_perm xor1
  x = dpp_add<0x4E>(x);   // quad_perm xor2
  x = dpp_add<0x124>(x);  // row_ror:4
  x = dpp_add<0x128>(x);  // row_ror:8
  x = dpp_add<0x142>(x);  // row_bcast:15
  x = dpp_add<0x143>(x);  // row_bcast:31
  return x;
}
__device__ __forceinline__ float bcast63(float x){
  return __int_as_float(__builtin_amdgcn_readlane(__float_as_int(x), 63));
}
__device__ __forceinline__ float rdl(float v, int l){
  return __int_as_float(__builtin_amdgcn_readlane(__float_as_int(v), l));
}
__device__ __forceinline__ C2 rdl2(C2 v, int l){
  return { rdl(v.re, l), rdl(v.im, l) };
}
// lane i <- lane i-1, lane0 <- 0   (wave_shr:1)
__device__ __forceinline__ float shr1(float x){
  return __int_as_float(__builtin_amdgcn_update_dpp(0, __float_as_int(x), 0x138, 0xF, 0xF, true));
}

__global__ __launch_bounds__(512) void ssm_dplr_kernel(
    const float* __restrict__ A_real, const float* __restrict__ A_imag,
    const float* __restrict__ B_real, const float* __restrict__ B_imag,
    const float* __restrict__ P_real, const float* __restrict__ P_imag,
    const float* __restrict__ C_real, const float* __restrict__ C_imag,
    const float* __restrict__ log_dt, float* __restrict__ out)
{
    const int h    = blockIdx.x;
    const int t    = threadIdx.x;
    const int lane = t & 63;
    const int widu = __builtin_amdgcn_readfirstlane(t >> 6);   // SGPR wave id 0..7

    extern __shared__ char sm[];
    float2* Abuf = (float2*)sm;              // 64x64: G powers, later X   [32 KB]
    float2* Cs   = (float2*)(sm + 32768);    // 32x64 C_i rows             [16 KB]
    float2* prt  = (float2*)(sm + 49152);    // 2 x 512 partials           [ 8 KB]
    float2* TgA  = (float2*)(sm + 57344);    // 64
    float2* TpA  = TgA + 64;                 // 64

    // ---------------- setup (every wave, per-lane n = lane) ----------------
    const int idx = h * 64 + lane;
    const float dt = expf(log_dt[h]);
    const float c  = 0.5f * dt;

    const C2 lam = { -A_real[idx], -A_imag[idx] };
    const C2 p   = {  P_real[idx],  P_imag[idx] };
    const C2 Bv  = {  B_real[idx],  B_imag[idx] };
    const C2 Cv  = {  C_real[idx],  C_imag[idx] };
    const C2 pc  = { p.re, -p.im };

    const C2 d = cinv(C2{ 1.0f - c*lam.re, -c*lam.im });
    const C2 g = cmul(d, C2{ 1.0f + c*lam.re, c*lam.im });   // diag of dA

    C2 sv = cscale(p.re*p.re + p.im*p.im, d);
    C2 uv = cmul(cmul(d, pc), Bv);
    sv.re = bcast63(wave_sum63(sv.re)); sv.im = bcast63(wave_sum63(sv.im));
    uv.re = bcast63(wave_sum63(uv.re)); uv.im = bcast63(wave_sum63(uv.im));

    const C2 beta  = cscale(c, cinv(C2{ 1.0f + c*sv.re, c*sv.im }));
    const C2 bs    = cmul(beta, sv);
    const C2 gamma = { -c*(1.0f - bs.re), c*bs.im };

    const C2 q  = cmul(d, p);
    const C2 r  = cmul(pc, csub(gamma, cmul(beta, g)));
    const C2 x0 = cscale(dt, csub(cmul(d, Bv), cmul(cmul(beta, uv), q)));  // dB
    const C2 rq = cmul(r, q);
    const C2 rx = cmul(r, x0);

    const C2 g2  = cmul(g,  g);
    const C2 g4  = cmul(g2, g2);
    const C2 g8  = cmul(g4, g4);
    const C2 g16 = cmul(g8, g8);
    const C2 g32 = cmul(g16,g16);
    const C2 g64 = cmul(g32,g32);

    // ---------------- G-gen: G[j][n] = g_n^j, rows j in [8w, 8w+8) ----------------
    {
        C2 cur = {1.0f, 0.0f};
        if (widu & 1) cur = g8;
        if (widu & 2) cur = cmul(cur, g16);
        if (widu & 4) cur = cmul(cur, g32);
        #pragma unroll
        for (int jj = 0; jj < 8; ++jj) {
            const int j = 8*widu + jj;
            Abuf[j*64 + ((lane + j) & 63)] = st2(cur);   // rotated columns
            cur = cmul(cur, g);
        }
    }
    __syncthreads();   // B1

    // ---------------- w_j, a_j partials (lane = j), broadcasts via readlane ----------------
    {
        C2 accw = {0,0}, acca = {0,0};
        #pragma unroll
        for (int kk = 0; kk < 8; ++kk) {
            const int n = 8*widu + kk;
            const C2 Gv = ld2(Abuf[lane*64 + ((n + lane) & 63)]);
            const C2 fq = rdl2(rq, n);
            const C2 fx = rdl2(rx, n);
            accw = cadd(accw, cmul(Gv, fq));
            acca = cadd(acca, cmul(Gv, fx));
        }
        prt[widu*64 + lane]       = st2(accw);
        prt[512 + widu*64 + lane] = st2(acca);
    }
    __syncthreads();   // B2

    // ---------------- solves (waves 0,1) + dependent solo phases ----------------
    C2 so = {0.0f, 0.0f};     // wave0: sigma_lane; wave1: tau_lane
    if (widu < 2) {
        // reduce w (both waves need the kernel), a only for wave0
        C2 wl = {0,0};
        {
            const float2 w0 = prt[lane],       w1 = prt[64+lane],  w2 = prt[128+lane], w3 = prt[192+lane];
            const float2 w4 = prt[256+lane],   w5 = prt[320+lane], w6 = prt[384+lane], w7 = prt[448+lane];
            wl.re = ((w0.x+w1.x)+(w2.x+w3.x)) + ((w4.x+w5.x)+(w6.x+w7.x));
            wl.im = ((w0.y+w1.y)+(w2.y+w3.y)) + ((w4.y+w5.y)+(w6.y+w7.y));
        }
        C2 va;
        if (widu == 0) {
            const float2 a0 = prt[512+lane],     a1 = prt[512+64+lane],  a2 = prt[512+128+lane], a3 = prt[512+192+lane];
            const float2 a4 = prt[512+256+lane], a5 = prt[512+320+lane], a6 = prt[512+384+lane], a7 = prt[512+448+lane];
            va.re = ((a0.x+a1.x)+(a2.x+a3.x)) + ((a4.x+a5.x)+(a6.x+a7.x));
            va.im = ((a0.y+a1.y)+(a2.y+a3.y)) + ((a4.y+a5.y)+(a6.y+a7.y));
        } else {
            va = wl;
        }
        // triangular-Toeplitz solve: v_j = rhs_j + sum_{i<j} w_{j-1-i} v_i
        C2 wsh = { shr1(wl.re), shr1(wl.im) };
        for (int j = 0; j < 64; ++j) {
            const float sr = rdl(va.re, j);
            const float si = rdl(va.im, j);
            if (lane == j) { so.re = sr; so.im = si; }
            va.re += wsh.re*sr - wsh.im*si;
            va.im += wsh.re*si + wsh.im*sr;
            wsh.re = shr1(wsh.re);
            wsh.im = shr1(wsh.im);
        }
    }
    if (widu == 0) {
        // X rebuild from own sigma registers: X_{j+1} = g.*X_j + sigma_j q
        C2 x = x0;
        for (int j = 0; j < 64; ++j) {
            Abuf[j*64 + ((lane + j) & 63)] = st2(x);
            const float sjr = rdl(so.re, j);
            const float sji = rdl(so.im, j);
            const float nr = g.re*x.re - g.im*x.im + sjr*q.re - sji*q.im;
            const float ni = g.re*x.im + g.im*x.re + sjr*q.im + sji*q.re;
            x.re = nr; x.im = ni;
        }
    } else if (widu == 1) {
        // T(z) = z * P(z), P from tau (own registers); T' = P + z P'
        C2 pp = rdl2(so, 0);
        C2 dd = {0,0};
        for (int i = 1; i <= 62; ++i) {
            const C2 ti = rdl2(so, i);
            const C2 nd = cadd(cmul(dd, g), pp);
            pp = cadd(cmul(pp, g), ti);
            dd = nd;
        }
        TgA[lane] = st2(cmul(g, pp));
        TpA[lane] = st2(cadd(pp, cmul(g, dd)));
    }
    __syncthreads();   // B3

    // ---------------- M build: Mk[k] = M[8w+k][lane] ----------------
    // M[n][m] = d_{nm} g64_n + q_n r_m [ (g64_n-g64_m) + (T(g_n)-T(g_m)) ] / (g_n-g_m)
    // M[n][n] = g64_n + q_n r_n ( 64 g_n^63 + T'(g_n) )
    C2 Mk[8];
    {
        const C2 Tgm = ld2(TgA[lane]);
        #pragma unroll
        for (int k = 0; k < 8; ++k) {
            const int n = 8*widu + k;
            const C2 gn   = rdl2(g,   n);
            const C2 qn   = rdl2(q,   n);
            const C2 g64n = rdl2(g64, n);
            const C2 Tgn  = rdl2(Tgm, n);
            const C2 idm  = cinv(csub(gn, g));     // inf on n==lane, overwritten below
            const C2 num  = cmul(r, cadd(csub(g64n, g64), csub(Tgn, Tgm)));
            Mk[k] = cmul(cmul(qn, num), idm);
        }
        if ((lane >> 3) == widu) {
            const int k0 = lane & 7;
            const C2 Tp  = ld2(TpA[lane]);
            const C2 g63 = cmul(g64, cinv(g));
            const C2 S   = cmul(r, cadd(cscale(64.0f, g63), Tp));
            Mk[k0] = cadd(g64, cmul(q, S));
        }
    }

    // ---------------- C chain: C_{i+1} = C_i M ----------------
    C2 Ci = Cv;
    for (int i = 0; i < 32; ++i) {
        if (widu == 0) Cs[i*64 + lane] = st2(Ci);
        if (i == 31) break;
        C2 acc = {0,0};
        #pragma unroll
        for (int k = 0; k < 8; ++k) {
            const float cr  = rdl(Ci.re, 8*widu + k);
            const float cim = rdl(Ci.im, 8*widu + k);
            acc.re += cr*Mk[k].re - cim*Mk[k].im;
            acc.im += cr*Mk[k].im + cim*Mk[k].re;
        }
        float2* buf = prt + (i & 1)*512;
        buf[widu*64 + lane] = st2(acc);
        __syncthreads();
        const float2 p0 = buf[lane],     p1 = buf[64+lane],  p2 = buf[128+lane], p3 = buf[192+lane];
        const float2 p4 = buf[256+lane], p5 = buf[320+lane], p6 = buf[384+lane], p7 = buf[448+lane];
        Ci.re = ((p0.x+p1.x)+(p2.x+p3.x)) + ((p4.x+p5.x)+(p6.x+p7.x));
        Ci.im = ((p0.y+p1.y)+(p2.y+p3.y)) + ((p4.y+p5.y)+(p6.y+p7.y));
    }
    __syncthreads();   // B4

    // ---------------- output: K[64i+j] = 2 Re( sum_n C_i[n] X_j[n] ), i in [4w,4w+4) ----------------
    {
        const int j = lane;
        C2 Csr[4];
        #pragma unroll
        for (int rr = 0; rr < 4; ++rr) Csr[rr] = ld2(Cs[(4*widu + rr)*64 + lane]);
        float accK[4] = {0,0,0,0};
        #pragma unroll 8
        for (int n = 0; n < 64; ++n) {
            const float2 xv = Abuf[j*64 + ((n + j) & 63)];
            #pragma unroll
            for (int rr = 0; rr < 4; ++rr) {
                accK[rr] += rdl(Csr[rr].re, n)*xv.x - rdl(Csr[rr].im, n)*xv.y;
            }
        }
        float* outh = out + h * LL;
        #pragma unroll
        for (int rr = 0; rr < 4; ++rr) {
            outh[(4*widu + rr)*64 + j] = 2.0f * accK[rr];
        }
    }
}

extern "C" void kernel_launch(void* const* d_in, const int* in_sizes, int n_in,
                              void* d_out, int out_size, void* d_ws, size_t ws_size,
                              hipStream_t stream) {
    const float* A_real = (const float*)d_in[0];
    const float* A_imag = (const float*)d_in[1];
    const float* B_real = (const float*)d_in[2];
    const float* B_imag = (const float*)d_in[3];
    const float* P_real = (const float*)d_in[4];
    const float* P_imag = (const float*)d_in[5];
    const float* C_real = (const float*)d_in[6];
    const float* C_imag = (const float*)d_in[7];
    const float* log_dt = (const float*)d_in[8];
    float* out = (float*)d_out;

    const size_t lds = 57344 + 128*sizeof(float2);   // 58368 B
    ssm_dplr_kernel<<<256, 512, lds, stream>>>(
        A_real, A_imag, B_real, B_imag, P_real, P_imag,
        C_real, C_imag, log_dt, out);
}